// Round 8
// baseline (119.923 us; speedup 1.0000x reference)
//
#include <hip/hip_runtime.h>
#include <hip/hip_bf16.h>

// Problem constants (reference: N,E,H,L = 64,64,768,512; eps=1e-12)
#define Nn 64
#define Ee 64
#define Hh 768
#define Ll 512
#define NEH (Nn * Ee * Hh) // 3145728 state elems
#define NEL (Nn * Ee * Ll) // 2097152 mapping elems

typedef __attribute__((ext_vector_type(8))) short bf16x8; // 8 bf16 = 4 VGPRs (MFMA A/B frag)
typedef __attribute__((ext_vector_type(4))) float f32x4;  // MFMA C/D frag

// ---------------------------------------------------------------------------
// MEASUREMENT ROUND R8: both kernels wrapped in idempotent rep-loops so BOTH
// out-rank the harness's 57-62us poison fills in BOTH rocprof passes:
//   gemm_ln x3 (~104us, rank 1) -> FETCH_SIZE + MfmaUtil + VALUBusy + Occ
//   cvt_transpose x10 (~70us, rank 2) -> its true per-pass cost + counters
// Structure is EXACTLY R3 (best known, 43.1us total). Next round drops reps
// and applies the fix the counters select.
// ---------------------------------------------------------------------------
__global__ __launch_bounds__(256) void cvt_transpose(
    const float* __restrict__ state, const float* __restrict__ mapping,
    __hip_bfloat16* __restrict__ sT, __hip_bfloat16* __restrict__ mT)
{
    __shared__ unsigned short lds[64][66]; // [x][e]

    int b = blockIdx.x;
    const float* src;
    __hip_bfloat16* dst;
    int W, x0;
    if (b < Nn * (Hh / 64)) {            // state tiles
        int n = b / (Hh / 64);
        x0 = (b % (Hh / 64)) * 64;
        src = state + (size_t)n * Ee * Hh;
        dst = sT + (size_t)n * Hh * Ee;
        W = Hh;
    } else {                              // mapping tiles
        b -= Nn * (Hh / 64);
        int n = b / (Ll / 64);
        x0 = (b % (Ll / 64)) * 64;
        src = mapping + (size_t)n * Ee * Ll;
        dst = mT + (size_t)n * Ll * Ee;
        W = Ll;
    }

    const int xr = (threadIdx.x & 31) * 2;
    const int er = threadIdx.x >> 5;  // 0..7
    const int e4 = (threadIdx.x & 15) * 4;
    const int xw = threadIdx.x >> 4;   // 0..15
    unsigned short* dsts = reinterpret_cast<unsigned short*>(dst);

#pragma unroll 1
    for (int rep = 0; rep < 10; ++rep) {
        asm volatile("" ::: "memory");   // force full re-execution per rep
        // Read phase: each thread loads float2 (2 x's) of one e-row.
#pragma unroll
        for (int i = 0; i < 8; ++i) {
            int e = i * 8 + er;
            float2 v = *reinterpret_cast<const float2*>(src + (size_t)e * W + x0 + xr);
            union { __hip_bfloat16 b16; unsigned short u; } c0, c1;
            c0.b16 = __float2bfloat16(v.x);
            c1.b16 = __float2bfloat16(v.y);
            lds[xr][e]     = c0.u;
            lds[xr + 1][e] = c1.u;
        }
        __syncthreads();

        // Write phase: each thread packs 4 bf16 (contiguous e) -> one 8B store.
#pragma unroll
        for (int i = 0; i < 4; ++i) {
            int x = i * 16 + xw;
            uint2 v;
            v.x = *reinterpret_cast<const unsigned int*>(&lds[x][e4]);
            v.y = *reinterpret_cast<const unsigned int*>(&lds[x][e4 + 2]);
            *reinterpret_cast<uint2*>(dsts + (size_t)(x0 + x) * Ee + e4) = v;
        }
        __syncthreads();   // WAR: next rep's read-phase rewrites lds
    }
}

// ---------------------------------------------------------------------------
// R3-structure gemm_ln (direct stores, 32-l tiles, 152 VGPR) x3 rep.
// ---------------------------------------------------------------------------
__global__ __launch_bounds__(256) void gemm_ln(
    const __hip_bfloat16* __restrict__ sT, // [N][H][E]
    const __hip_bfloat16* __restrict__ mT, // [N][L][E]
    const float* __restrict__ gamma,
    const float* __restrict__ beta,
    float* __restrict__ out)               // [N][L][H]
{
    __shared__ float redS[32][4];
    __shared__ float redQ[32][4];

    const int p    = blockIdx.x;
    const int n    = ((p >> 7) << 3) | (p & 7);
    const int l0   = ((p >> 3) & 15) << 5; // 32 rows per tile
    const int tid  = threadIdx.x;
    const int w    = tid >> 6;        // wave 0..3
    const int lane = tid & 63;
    const int g    = lane >> 4;       // k-group 0..3 (also h sub-offset in D)
    const int c    = lane & 15;       // operand row index (h for A, l for B)

#pragma unroll 1
    for (int rep = 0; rep < 3; ++rep) {
        asm volatile("" ::: "memory");   // force full re-execution per rep

        // B fragments (mapping rows l0+u*16+c), k = 8*g + j and +32
        bf16x8 b0[2], b1[2];
#pragma unroll
        for (int u = 0; u < 2; ++u) {
            const __hip_bfloat16* Brow = mT + (size_t)(n * Ll + l0 + u * 16 + c) * Ee + g * 8;
            b0[u] = *reinterpret_cast<const bf16x8*>(Brow);
            b1[u] = *reinterpret_cast<const bf16x8*>(Brow + 32);
        }

        f32x4 acc[12][2];
#pragma unroll
        for (int t = 0; t < 12; ++t)
#pragma unroll
            for (int u = 0; u < 2; ++u) acc[t][u] = (f32x4){0.f, 0.f, 0.f, 0.f};

        const __hip_bfloat16* Abase = sT + (size_t)(n * Hh + w * 192 + c) * Ee + g * 8;
#pragma unroll
        for (int t = 0; t < 12; ++t) {
            const __hip_bfloat16* ap = Abase + (size_t)t * 16 * Ee;
            bf16x8 a0 = *reinterpret_cast<const bf16x8*>(ap);
            bf16x8 a1 = *reinterpret_cast<const bf16x8*>(ap + 32);
#pragma unroll
            for (int u = 0; u < 2; ++u) {
                acc[t][u] = __builtin_amdgcn_mfma_f32_16x16x32_bf16(a0, b0[u], acc[t][u], 0, 0, 0);
                acc[t][u] = __builtin_amdgcn_mfma_f32_16x16x32_bf16(a1, b1[u], acc[t][u], 0, 0, 0);
            }
        }

        // ---------------- LayerNorm over H=768 ----------------
        float s[2] = {0.f, 0.f}, q[2] = {0.f, 0.f};
#pragma unroll
        for (int t = 0; t < 12; ++t)
#pragma unroll
            for (int u = 0; u < 2; ++u)
#pragma unroll
                for (int r = 0; r < 4; ++r) {
                    float v = acc[t][u][r];
                    s[u] += v;
                    q[u] += v * v;
                }
#pragma unroll
        for (int off = 16; off < 64; off <<= 1)
#pragma unroll
            for (int u = 0; u < 2; ++u) {
                s[u] += __shfl_xor(s[u], off, 64);
                q[u] += __shfl_xor(q[u], off, 64);
            }
        if (g == 0) {
#pragma unroll
            for (int u = 0; u < 2; ++u) {
                redS[u * 16 + c][w] = s[u];
                redQ[u * 16 + c][w] = q[u];
            }
        }
        __syncthreads();

        float mu[2], rstd[2];
#pragma unroll
        for (int u = 0; u < 2; ++u) {
            int li = u * 16 + c;
            float S = redS[li][0] + redS[li][1] + redS[li][2] + redS[li][3];
            float Q = redQ[li][0] + redQ[li][1] + redQ[li][2] + redQ[li][3];
            float m = S * (1.f / Hh);
            float v = Q * (1.f / Hh) - m * m;
            mu[u]   = m;
            rstd[u] = rsqrtf(v + 1e-12f);
        }

        // ---------------- Epilogue: normalize + gamma/beta + float4 stores ----------------
#pragma unroll
        for (int t = 0; t < 12; ++t) {
            int hb = w * 192 + t * 16 + g * 4;
            f32x4 gm = *reinterpret_cast<const f32x4*>(gamma + hb);
            f32x4 bt = *reinterpret_cast<const f32x4*>(beta + hb);
#pragma unroll
            for (int u = 0; u < 2; ++u) {
                f32x4 v;
#pragma unroll
                for (int r = 0; r < 4; ++r)
                    v[r] = (acc[t][u][r] - mu[u]) * rstd[u] * gm[r] + bt[r];
                *reinterpret_cast<f32x4*>(
                    out + (size_t)(n * Ll + l0 + u * 16 + c) * Hh + hb) = v;
            }
        }
        __syncthreads();   // keep reps' redS/redQ usage disjoint
    }
}

extern "C" void kernel_launch(void* const* d_in, const int* in_sizes, int n_in,
                              void* d_out, int out_size, void* d_ws, size_t ws_size,
                              hipStream_t stream)
{
    const float* state   = (const float*)d_in[0]; // (N,E,H)
    const float* mapping = (const float*)d_in[1]; // (N,E,L)
    const float* gamma   = (const float*)d_in[2]; // (H,)
    const float* beta    = (const float*)d_in[3]; // (H,)
    float* out           = (float*)d_out;         // (N,L,H)

    __hip_bfloat16* sT = (__hip_bfloat16*)d_ws;   // N*H*E bf16
    __hip_bfloat16* mT = sT + NEH;                // N*L*E bf16  (total ws use: 10.5 MB)

    const int tiles = Nn * (Hh / 64) + Nn * (Ll / 64); // 768 + 512 = 1280
    cvt_transpose<<<tiles, 256, 0, stream>>>(state, mapping, sT, mT);
    gemm_ln<<<Nn * (Ll / 32), 256, 0, stream>>>(sT, mT, gamma, beta, out);
}

// Round 9
// 52.949 us; speedup vs baseline: 2.2649x; 2.2649x over previous
//
#include <hip/hip_runtime.h>
#include <hip/hip_bf16.h>

// Problem constants (reference: N,E,H,L = 64,64,768,512; eps=1e-12)
#define Nn 64
#define Ee 64
#define Hh 768
#define Ll 512
#define NEH (Nn * Ee * Hh) // 3145728 state elems
#define NEL (Nn * Ee * Ll) // 2097152 mapping elems

typedef __attribute__((ext_vector_type(8))) short bf16x8; // 8 bf16 = 4 VGPRs (MFMA A/B frag)
typedef __attribute__((ext_vector_type(4))) float f32x4;  // MFMA C/D frag

// ---------------------------------------------------------------------------
// Pre-pass: fp32 -> bf16 convert + transpose, LDS-tiled, both sides coalesced.
//   sT[n][h][e]  (H x E per n)   mT[n][l][e]  (L x E per n)
// (Unchanged R3 form; bounded <5.7us/pass by R8's rank evidence.)
// ---------------------------------------------------------------------------
__global__ __launch_bounds__(256) void cvt_transpose(
    const float* __restrict__ state, const float* __restrict__ mapping,
    __hip_bfloat16* __restrict__ sT, __hip_bfloat16* __restrict__ mT)
{
    __shared__ unsigned short lds[64][66]; // [x][e]

    int b = blockIdx.x;
    const float* src;
    __hip_bfloat16* dst;
    int W, x0;
    if (b < Nn * (Hh / 64)) {            // state tiles
        int n = b / (Hh / 64);
        x0 = (b % (Hh / 64)) * 64;
        src = state + (size_t)n * Ee * Hh;
        dst = sT + (size_t)n * Hh * Ee;
        W = Hh;
    } else {                              // mapping tiles
        b -= Nn * (Hh / 64);
        int n = b / (Ll / 64);
        x0 = (b % (Ll / 64)) * 64;
        src = mapping + (size_t)n * Ee * Ll;
        dst = mT + (size_t)n * Ll * Ee;
        W = Ll;
    }

    // Read phase: each thread loads float2 (2 x's) of one e-row.
    const int xr = (threadIdx.x & 31) * 2;
    const int er = threadIdx.x >> 5;  // 0..7
#pragma unroll
    for (int i = 0; i < 8; ++i) {
        int e = i * 8 + er;
        float2 v = *reinterpret_cast<const float2*>(src + (size_t)e * W + x0 + xr);
        union { __hip_bfloat16 b16; unsigned short u; } c0, c1;
        c0.b16 = __float2bfloat16(v.x);
        c1.b16 = __float2bfloat16(v.y);
        lds[xr][e]     = c0.u;
        lds[xr + 1][e] = c1.u;
    }
    __syncthreads();

    // Write phase: each thread packs 4 bf16 (contiguous e) -> one 8B store.
    const int e4 = (threadIdx.x & 15) * 4;
    const int xw = threadIdx.x >> 4;   // 0..15
    unsigned short* dsts = reinterpret_cast<unsigned short*>(dst);
#pragma unroll
    for (int i = 0; i < 4; ++i) {
        int x = i * 16 + xw;
        uint2 v;
        v.x = *reinterpret_cast<const unsigned int*>(&lds[x][e4]);
        v.y = *reinterpret_cast<const unsigned int*>(&lds[x][e4 + 2]);
        *reinterpret_cast<uint2*>(dsts + (size_t)(x0 + x) * Ee + e4) = v;
    }
}

// ---------------------------------------------------------------------------
// Fused GEMM (out[n,l,h] = sum_e mapping[n,e,l]*state[n,e,h]) + LayerNorm(H).
//
// R9 (from R8 counters: Occupancy 10.7% = 1 block/CU; FETCH tiny; pipes idle
// => serialized compute->drain per block was the 33us):
//   - 16-l tiles: acc 12 frags = 48 accum regs (was 96) => ~120 total regs.
//   - __launch_bounds__(256,3): 3 waves/EU => 3 blocks/CU co-resident, so
//     one block's MFMA/LN overlaps another's store drain (steady-state
//     write stream instead of synchronized bursts).
//   - REGULAR cached float4 stores (R7's NT stores regressed: bypassing L2
//     removed the burst buffer).
// Each wave: h slice [w*192,(w+1)*192), 12 16x16 tiles, K=64 (2 MFMA/tile).
// ---------------------------------------------------------------------------
__global__ __launch_bounds__(256, 3) void gemm_ln(
    const __hip_bfloat16* __restrict__ sT, // [N][H][E]
    const __hip_bfloat16* __restrict__ mT, // [N][L][E]
    const float* __restrict__ gamma,
    const float* __restrict__ beta,
    float* __restrict__ out)               // [N][L][H]
{
    __shared__ float redS[16][4];
    __shared__ float redQ[16][4];

    const int p    = blockIdx.x;
    const int n    = ((p >> 8) << 3) | (p & 7);  // XCD-grouped, bijective on [0,2048)
    const int l0   = ((p >> 3) & 31) << 4;       // 16 rows per tile
    const int tid  = threadIdx.x;
    const int w    = tid >> 6;        // wave 0..3
    const int lane = tid & 63;
    const int g    = lane >> 4;       // k-group 0..3 (also h sub-offset in D)
    const int c    = lane & 15;       // operand row index (h for A, l for B)

    // B fragments (mapping row l0+c), k = 8*g + j and +32
    const __hip_bfloat16* Brow = mT + (size_t)(n * Ll + l0 + c) * Ee + g * 8;
    const bf16x8 b0 = *reinterpret_cast<const bf16x8*>(Brow);
    const bf16x8 b1 = *reinterpret_cast<const bf16x8*>(Brow + 32);

    f32x4 acc[12];
#pragma unroll
    for (int t = 0; t < 12; ++t) acc[t] = (f32x4){0.f, 0.f, 0.f, 0.f};

    const __hip_bfloat16* Abase = sT + (size_t)(n * Hh + w * 192 + c) * Ee + g * 8;
#pragma unroll
    for (int t = 0; t < 12; ++t) {
        const __hip_bfloat16* ap = Abase + (size_t)t * 16 * Ee;
        bf16x8 a0 = *reinterpret_cast<const bf16x8*>(ap);
        bf16x8 a1 = *reinterpret_cast<const bf16x8*>(ap + 32);
        acc[t] = __builtin_amdgcn_mfma_f32_16x16x32_bf16(a0, b0, acc[t], 0, 0, 0);
        acc[t] = __builtin_amdgcn_mfma_f32_16x16x32_bf16(a1, b1, acc[t], 0, 0, 0);
    }

    // ---------------- LayerNorm over H=768 ----------------
    // Lane holds l row (l0+c) and h values {w*192 + t*16 + g*4 + r}.
    float s = 0.f, q = 0.f;
#pragma unroll
    for (int t = 0; t < 12; ++t)
#pragma unroll
        for (int r = 0; r < 4; ++r) {
            float v = acc[t][r];
            s += v;
            q += v * v;
        }
    // Sum over g (lanes c, c+16, c+32, c+48): two butterfly steps.
#pragma unroll
    for (int off = 16; off < 64; off <<= 1) {
        s += __shfl_xor(s, off, 64);
        q += __shfl_xor(q, off, 64);
    }
    // Cross-wave combine: each wave has the partial over its 192-h slice.
    if (g == 0) {
        redS[c][w] = s;
        redQ[c][w] = q;
    }
    __syncthreads();

    const float S = redS[c][0] + redS[c][1] + redS[c][2] + redS[c][3];
    const float Q = redQ[c][0] + redQ[c][1] + redQ[c][2] + redQ[c][3];
    const float mu   = S * (1.f / Hh);
    const float var  = Q * (1.f / Hh) - mu * mu;
    const float rstd = rsqrtf(var + 1e-12f);

    // ---------------- Epilogue: normalize + gamma/beta + float4 stores ----------------
    float* orow = out + (size_t)(n * Ll + l0 + c) * Hh;
#pragma unroll
    for (int t = 0; t < 12; ++t) {
        int hb = w * 192 + t * 16 + g * 4;
        f32x4 gm = *reinterpret_cast<const f32x4*>(gamma + hb);
        f32x4 bt = *reinterpret_cast<const f32x4*>(beta + hb);
        f32x4 v;
#pragma unroll
        for (int r = 0; r < 4; ++r)
            v[r] = (acc[t][r] - mu) * rstd * gm[r] + bt[r];
        *reinterpret_cast<f32x4*>(orow + hb) = v;
    }
}

extern "C" void kernel_launch(void* const* d_in, const int* in_sizes, int n_in,
                              void* d_out, int out_size, void* d_ws, size_t ws_size,
                              hipStream_t stream)
{
    const float* state   = (const float*)d_in[0]; // (N,E,H)
    const float* mapping = (const float*)d_in[1]; // (N,E,L)
    const float* gamma   = (const float*)d_in[2]; // (H,)
    const float* beta    = (const float*)d_in[3]; // (H,)
    float* out           = (float*)d_out;         // (N,L,H)

    __hip_bfloat16* sT = (__hip_bfloat16*)d_ws;   // N*H*E bf16
    __hip_bfloat16* mT = sT + NEH;                // N*L*E bf16  (total ws use: 10.5 MB)

    const int tiles = Nn * (Hh / 64) + Nn * (Ll / 64); // 768 + 512 = 1280
    cvt_transpose<<<tiles, 256, 0, stream>>>(state, mapping, sT, mT);
    gemm_ln<<<Nn * (Ll / 16), 256, 0, stream>>>(sT, mT, gamma, beta, out);
}

// Round 10
// 41.822 us; speedup vs baseline: 2.8675x; 1.2661x over previous
//
#include <hip/hip_runtime.h>
#include <hip/hip_bf16.h>

// Problem constants (reference: N,E,H,L = 64,64,768,512; eps=1e-12)
#define Nn 64
#define Ee 64
#define Hh 768
#define Ll 512
#define NEH (Nn * Ee * Hh) // 3145728 state elems
#define NEL (Nn * Ee * Ll) // 2097152 mapping elems

typedef __attribute__((ext_vector_type(8))) short bf16x8; // 8 bf16 = 4 VGPRs (MFMA A/B frag)
typedef __attribute__((ext_vector_type(4))) float f32x4;  // MFMA C/D frag

// ---------------------------------------------------------------------------
// Pre-pass: fp32 -> bf16 convert + transpose, LDS-tiled, both sides coalesced.
//   sT[n][h][e]  (H x E per n)   mT[n][l][e]  (L x E per n)
// (R3 form, measured <5.7us/pass by R8 rank evidence.)
// ---------------------------------------------------------------------------
__global__ __launch_bounds__(256) void cvt_transpose(
    const float* __restrict__ state, const float* __restrict__ mapping,
    __hip_bfloat16* __restrict__ sT, __hip_bfloat16* __restrict__ mT)
{
    __shared__ unsigned short lds[64][66]; // [x][e]

    int b = blockIdx.x;
    const float* src;
    __hip_bfloat16* dst;
    int W, x0;
    if (b < Nn * (Hh / 64)) {            // state tiles
        int n = b / (Hh / 64);
        x0 = (b % (Hh / 64)) * 64;
        src = state + (size_t)n * Ee * Hh;
        dst = sT + (size_t)n * Hh * Ee;
        W = Hh;
    } else {                              // mapping tiles
        b -= Nn * (Hh / 64);
        int n = b / (Ll / 64);
        x0 = (b % (Ll / 64)) * 64;
        src = mapping + (size_t)n * Ee * Ll;
        dst = mT + (size_t)n * Ll * Ee;
        W = Ll;
    }

    // Read phase: each thread loads float2 (2 x's) of one e-row.
    const int xr = (threadIdx.x & 31) * 2;
    const int er = threadIdx.x >> 5;  // 0..7
#pragma unroll
    for (int i = 0; i < 8; ++i) {
        int e = i * 8 + er;
        float2 v = *reinterpret_cast<const float2*>(src + (size_t)e * W + x0 + xr);
        union { __hip_bfloat16 b16; unsigned short u; } c0, c1;
        c0.b16 = __float2bfloat16(v.x);
        c1.b16 = __float2bfloat16(v.y);
        lds[xr][e]     = c0.u;
        lds[xr + 1][e] = c1.u;
    }
    __syncthreads();

    // Write phase: each thread packs 4 bf16 (contiguous e) -> one 8B store.
    const int e4 = (threadIdx.x & 15) * 4;
    const int xw = threadIdx.x >> 4;   // 0..15
    unsigned short* dsts = reinterpret_cast<unsigned short*>(dst);
#pragma unroll
    for (int i = 0; i < 4; ++i) {
        int x = i * 16 + xw;
        uint2 v;
        v.x = *reinterpret_cast<const unsigned int*>(&lds[x][e4]);
        v.y = *reinterpret_cast<const unsigned int*>(&lds[x][e4 + 2]);
        *reinterpret_cast<uint2*>(dsts + (size_t)(x0 + x) * Ee + e4) = v;
    }
}

// ---------------------------------------------------------------------------
// Fused GEMM (out[n,l,h] = sum_e mapping[n,e,l]*state[n,e,h]) + LayerNorm(H).
// A = state frag (rows = h), B = mapping frag (cols = l); lane's f32x4 acc is
// 4 consecutive h -> direct float4 stores. EXACT R3 tile/math (best known).
//
// R10: PERSISTENT BLOCKS. R8 counters (FETCH 1.7MB, WRITE clean 98MB, pipes
// idle, 2.9TB/s) + R9's occupancy-counterexample localize the loss to the
// end-of-block store drain: waves sit in vmcnt(0)-before-endpgm while the CU
// has nothing to backfill. Fix: grid=512 (2 blocks/CU, all resident), each
// block does 2 tiles of the SAME n back-to-back. Tile i's stores drain under
// tile i+1's load/MFMA phase; no endpgm between. redS/redQ double-buffered
// by tile index (no extra barrier -> no extra forced drain point).
// #pragma unroll 1 keeps register pressure at the single-tile (R3) level.
// 8 blocks per n at block-ids == n (mod 8) -> same XCD -> sT[n] L2-resident.
// ---------------------------------------------------------------------------
__global__ __launch_bounds__(256) void gemm_ln(
    const __hip_bfloat16* __restrict__ sT, // [N][H][E]
    const __hip_bfloat16* __restrict__ mT, // [N][L][E]
    const float* __restrict__ gamma,
    const float* __restrict__ beta,
    float* __restrict__ out)               // [N][L][H]
{
    __shared__ float redS[2][32][4];
    __shared__ float redQ[2][32][4];

    const int j    = blockIdx.x;                  // 0..511 persistent
    const int n    = ((j >> 6) << 3) | (j & 7);   // 8 blocks per n, same XCD slot
    const int ltp  = (j >> 3) & 7;                // l-tile pair index (0..7)
    const int tid  = threadIdx.x;
    const int w    = tid >> 6;        // wave 0..3
    const int lane = tid & 63;
    const int g    = lane >> 4;       // k-group 0..3 (also h sub-offset in D)
    const int c    = lane & 15;       // operand row index (h for A, l for B)

#pragma unroll 1
    for (int it = 0; it < 2; ++it) {
        const int l0 = ((ltp << 1) | it) << 5;    // 32 rows per tile

        // B fragments (mapping rows l0+u*16+c), k = 8*g + j and +32
        bf16x8 b0[2], b1[2];
#pragma unroll
        for (int u = 0; u < 2; ++u) {
            const __hip_bfloat16* Brow = mT + (size_t)(n * Ll + l0 + u * 16 + c) * Ee + g * 8;
            b0[u] = *reinterpret_cast<const bf16x8*>(Brow);
            b1[u] = *reinterpret_cast<const bf16x8*>(Brow + 32);
        }

        f32x4 acc[12][2];
#pragma unroll
        for (int t = 0; t < 12; ++t)
#pragma unroll
            for (int u = 0; u < 2; ++u) acc[t][u] = (f32x4){0.f, 0.f, 0.f, 0.f};

        const __hip_bfloat16* Abase = sT + (size_t)(n * Hh + w * 192 + c) * Ee + g * 8;
#pragma unroll
        for (int t = 0; t < 12; ++t) {
            const __hip_bfloat16* ap = Abase + (size_t)t * 16 * Ee;
            bf16x8 a0 = *reinterpret_cast<const bf16x8*>(ap);
            bf16x8 a1 = *reinterpret_cast<const bf16x8*>(ap + 32);
#pragma unroll
            for (int u = 0; u < 2; ++u) {
                acc[t][u] = __builtin_amdgcn_mfma_f32_16x16x32_bf16(a0, b0[u], acc[t][u], 0, 0, 0);
                acc[t][u] = __builtin_amdgcn_mfma_f32_16x16x32_bf16(a1, b1[u], acc[t][u], 0, 0, 0);
            }
        }

        // ---------------- LayerNorm over H=768 ----------------
        // Lane holds l rows (l0+u*16+c) and h values {w*192 + t*16 + g*4 + r}.
        float s[2] = {0.f, 0.f}, q[2] = {0.f, 0.f};
#pragma unroll
        for (int t = 0; t < 12; ++t)
#pragma unroll
            for (int u = 0; u < 2; ++u)
#pragma unroll
                for (int r = 0; r < 4; ++r) {
                    float v = acc[t][u][r];
                    s[u] += v;
                    q[u] += v * v;
                }
        // Sum over g (lanes c, c+16, c+32, c+48): two butterfly steps.
#pragma unroll
        for (int off = 16; off < 64; off <<= 1)
#pragma unroll
            for (int u = 0; u < 2; ++u) {
                s[u] += __shfl_xor(s[u], off, 64);
                q[u] += __shfl_xor(q[u], off, 64);
            }
        // Cross-wave combine (parity-buffered: no end-of-iteration barrier
        // needed; buffer 'it' is next reused two tiles later, and the next
        // tile's own barrier orders everything in between).
        if (g == 0) {
#pragma unroll
            for (int u = 0; u < 2; ++u) {
                redS[it][u * 16 + c][w] = s[u];
                redQ[it][u * 16 + c][w] = q[u];
            }
        }
        __syncthreads();

        float mu[2], rstd[2];
#pragma unroll
        for (int u = 0; u < 2; ++u) {
            int li = u * 16 + c;
            float S = redS[it][li][0] + redS[it][li][1] + redS[it][li][2] + redS[it][li][3];
            float Q = redQ[it][li][0] + redQ[it][li][1] + redQ[it][li][2] + redQ[it][li][3];
            float m = S * (1.f / Hh);
            float v = Q * (1.f / Hh) - m * m;
            mu[u]   = m;
            rstd[u] = rsqrtf(v + 1e-12f);
        }

        // -------- Epilogue: normalize + gamma/beta + float4 stores --------
        // Stores drain during the NEXT tile's load/MFMA phase (no endpgm here).
#pragma unroll
        for (int t = 0; t < 12; ++t) {
            int hb = w * 192 + t * 16 + g * 4;
            f32x4 gm = *reinterpret_cast<const f32x4*>(gamma + hb);
            f32x4 bt = *reinterpret_cast<const f32x4*>(beta + hb);
#pragma unroll
            for (int u = 0; u < 2; ++u) {
                f32x4 v;
#pragma unroll
                for (int r = 0; r < 4; ++r)
                    v[r] = (acc[t][u][r] - mu[u]) * rstd[u] * gm[r] + bt[r];
                *reinterpret_cast<f32x4*>(
                    out + (size_t)(n * Ll + l0 + u * 16 + c) * Hh + hb) = v;
            }
        }
    }
}

extern "C" void kernel_launch(void* const* d_in, const int* in_sizes, int n_in,
                              void* d_out, int out_size, void* d_ws, size_t ws_size,
                              hipStream_t stream)
{
    const float* state   = (const float*)d_in[0]; // (N,E,H)
    const float* mapping = (const float*)d_in[1]; // (N,E,L)
    const float* gamma   = (const float*)d_in[2]; // (H,)
    const float* beta    = (const float*)d_in[3]; // (H,)
    float* out           = (float*)d_out;         // (N,L,H)

    __hip_bfloat16* sT = (__hip_bfloat16*)d_ws;   // N*H*E bf16
    __hip_bfloat16* mT = sT + NEH;                // N*L*E bf16  (total ws use: 10.5 MB)

    const int tiles = Nn * (Hh / 64) + Nn * (Ll / 64); // 768 + 512 = 1280
    cvt_transpose<<<tiles, 256, 0, stream>>>(state, mapping, sT, mT);
    gemm_ln<<<512, 256, 0, stream>>>(sT, mT, gamma, beta, out);
}